// Round 14
// baseline (121.201 us; speedup 1.0000x reference)
//
#include <hip/hip_runtime.h>
#include <hip/hip_bf16.h>

#define BB 16
#define CC 512
#define LL 2048

typedef float f32x4 __attribute__((ext_vector_type(4)));
typedef short s16x8 __attribute__((ext_vector_type(8)));

static __device__ __forceinline__ float bf2f(unsigned short u) {
    union { unsigned int i; float f; } v; v.i = ((unsigned int)u) << 16; return v.f;
}
static __device__ __forceinline__ unsigned short f2bf(float f) {
    union { float fv; unsigned int i; } v; v.fv = f;
    unsigned int x = v.i;
    return (unsigned short)((x + 0x7FFFu + ((x >> 16) & 1u)) >> 16);  // RNE
}

// ---------------- K0: cast gate_w f32 -> bf16 [512][512] ----------------
__global__ void k0_cast(const float* __restrict__ gw, unsigned short* __restrict__ gwb) {
    int i = blockIdx.x * 256 + threadIdx.x;
    if (i < CC * CC) gwb[i] = f2bf(gw[i]);
}

// ------- K1: RMS over C per (b,l); writes x_norm^T bf16, inv_rms, adx=sum_c x*lw -------
#define K1_ST 520   // ushort stride (1040 B, 16B-aligned)
__global__ __launch_bounds__(256) void k1_rms_t(
    const float* __restrict__ x, const float* __restrict__ pre_w,
    const float* __restrict__ lw,
    unsigned short* __restrict__ xnt, float* __restrict__ invr,
    float* __restrict__ adx) {
    __shared__ unsigned short tile[32 * K1_ST];   // [l][c] bf16, 33.3 KB
    __shared__ float red[32 * 33];
    __shared__ float red2[32 * 33];
    __shared__ float pwS[CC];
    __shared__ float lwS[CC];
    __shared__ float ivS[32];
    const int tid = threadIdx.x;
    const int b  = blockIdx.x >> 6;      // 64 l-tiles of 32
    const int lt = blockIdx.x & 63;
    const int l0 = lt * 32;
    const float* xb = x + (size_t)(b * CC) * LL + l0;

    for (int i = tid; i < CC; i += 256) { pwS[i] = pre_w[i]; lwS[i] = lw[i]; }
    __syncthreads();

    const int lq = tid & 7;      // l-quad: l = lq*4..+3
    const int cr = tid >> 3;     // 0..31
    f32x4 ssq = {0.f, 0.f, 0.f, 0.f};
    f32x4 sdx = {0.f, 0.f, 0.f, 0.f};
    #pragma unroll
    for (int p = 0; p < 16; ++p) {
        int c = p * 32 + cr;
        float lwc = lwS[c];
        f32x4 v = *(const f32x4*)(xb + (size_t)c * LL + lq * 4);
        #pragma unroll
        for (int r = 0; r < 4; ++r) {
            ssq[r] += v[r] * v[r];
            sdx[r] += v[r] * lwc;
            tile[(lq * 4 + r) * K1_ST + c] = f2bf(v[r]);
        }
    }
    #pragma unroll
    for (int r = 0; r < 4; ++r) {
        red[(lq * 4 + r) * 33 + cr]  = ssq[r];
        red2[(lq * 4 + r) * 33 + cr] = sdx[r];
    }
    __syncthreads();
    if (tid < 32) {
        float s = 0.f, sa = 0.f;
        #pragma unroll
        for (int g = 0; g < 32; ++g) { s += red[tid * 33 + g]; sa += red2[tid * 33 + g]; }
        float iv = rsqrtf(s * (1.0f / CC) + 1e-5f);
        ivS[tid] = iv;
        invr[b * LL + l0 + tid] = iv;
        adx[b * LL + l0 + tid] = sa;
    }
    __syncthreads();
    unsigned short* xo = xnt + ((size_t)b * LL + l0) * CC;
    #pragma unroll
    for (int p = 0; p < 8; ++p) {
        int g = p * 256 + tid;          // 2048 granules of 8 ushorts
        int l = g >> 6, c8 = (g & 63) * 8;
        s16x8 t = *(const s16x8*)&tile[l * K1_ST + c8];
        f32x4 w0 = *(const f32x4*)&pwS[c8];
        f32x4 w1 = *(const f32x4*)&pwS[c8 + 4];
        float iv = ivS[l];
        s16x8 o;
        #pragma unroll
        for (int r = 0; r < 4; ++r) {
            o[r]     = (short)f2bf(bf2f((unsigned short)t[r])     * iv * w0[r]);
            o[r + 4] = (short)f2bf(bf2f((unsigned short)t[r + 4]) * iv * w1[r]);
        }
        *(s16x8*)(xo + (size_t)l * CC + c8) = o;
    }
}

// ------- K2F: swapped-operand GEMM (M=l, N=d) + fused conv*gate + partials -------
// GEMM core = R6 verbatim (BK=32, 3-buf, counted vmcnt(8)); A=xnt rows (l),
// B=gwb rows (d) -> acc D-layout: lane owns d=...+lo (col), l=...+hi*4+r (row):
// 4 CONSECUTIVE l per cell -> conv reads are contiguous 12-value l-windows.
// Epilogue: stage xn [256 c][268 l] bf16 tile from x*iv*pw (iv=0 halo), per-lane
// 7-tap conv * silu(acc+gb), reduce over c (in-lane ni, shfl over lo, LDS over wn).
#define XST 268   // xnT l-stride (shorts); 536 B rows, b64-aligned
__global__ __launch_bounds__(512, 2) void k2f(
    const unsigned short* __restrict__ gwb,   // [512][512] (d,c)
    const unsigned short* __restrict__ xnt,   // [B][2048][512] (l,c)
    const float* __restrict__ x,              // [B][512][2048]
    const float* __restrict__ pre_w,
    const float* __restrict__ invr,
    const float* __restrict__ gate_b,
    const float* __restrict__ cw0, const float* __restrict__ cb0,
    const float* __restrict__ cw1, const float* __restrict__ cb1,
    const float* __restrict__ cw2, const float* __restrict__ cb2,
    const float* __restrict__ post_w, const float* __restrict__ lw,
    float* __restrict__ part) {
    union Sm {
        struct { unsigned short A[3][256 * 32], B[3][256 * 32]; } g;   // 96 KB
        struct {
            unsigned short xnT[256 * XST];   // [c][l], 134 KB
            float ivs[272];
            float tapS[256 * 9];             // t0..t6, bias, pwlw
            float gbS[256];
            float redS[256 * 4 * 2];         // [l][wn][2]
        } e;                                  // ~153 KB
    };
    __shared__ Sm sm;
    const int tid = threadIdx.x;
    const int w = tid >> 6, lane = tid & 63;
    const int lo = lane & 15, hi = lane >> 4;
    const int wm = w >> 2, wn = w & 3;           // 2M(l) x 4N(d) waves
    const int lt = blockIdx.x, dt = blockIdx.y, b = blockIdx.z;
    const int l0 = lt * 256, d0 = dt * 256;
    const unsigned short* Ab = xnt + (size_t)b * LL * CC;   // M rows: l0+row
    const unsigned short* Bb = gwb;                          // N rows: d0+row

    #define STG(kt_, buf_)                                                            \
        {                                                                             \
            _Pragma("unroll")                                                         \
            for (int s_ = 0; s_ < 2; ++s_) {                                          \
                int g_ = tid + s_ * 512;                                              \
                int row_ = g_ >> 2, gin_ = g_ & 3;                                    \
                int ks_ = (kt_) * 32 + ((gin_ ^ ((row_ >> 1) & 3)) * 8);              \
                __builtin_amdgcn_global_load_lds(                                     \
                    (const __attribute__((address_space(1))) void*)(Ab + (size_t)(l0 + row_) * CC + ks_), \
                    (__attribute__((address_space(3))) void*)(&sm.g.A[buf_][g_ * 8]), \
                    16, 0, 0);                                                        \
                __builtin_amdgcn_global_load_lds(                                     \
                    (const __attribute__((address_space(1))) void*)(Bb + (size_t)(d0 + row_) * CC + ks_), \
                    (__attribute__((address_space(3))) void*)(&sm.g.B[buf_][g_ * 8]), \
                    16, 0, 0);                                                        \
            }                                                                         \
        }

    f32x4 acc[8][4] = {};
    const int fsw = (lo >> 1) & 3;

    STG(0, 0);
    STG(1, 1);
    #pragma unroll
    for (int kt = 0; kt < 16; ++kt) {
        const int buf = kt % 3;
        if (kt < 14) {
            STG(kt + 2, (kt + 2) % 3);
            asm volatile("s_waitcnt vmcnt(8)" ::: "memory");
        } else if (kt == 14) {
            asm volatile("s_waitcnt vmcnt(4)" ::: "memory");
        } else {
            asm volatile("s_waitcnt vmcnt(0)" ::: "memory");
        }
        __builtin_amdgcn_s_barrier();
        s16x8 af[8], bfr[4];
        #pragma unroll
        for (int mi = 0; mi < 8; ++mi)
            af[mi] = *(const s16x8*)&sm.g.A[buf][(wm * 128 + mi * 16 + lo) * 32 + ((hi ^ fsw) * 8)];
        #pragma unroll
        for (int ni = 0; ni < 4; ++ni)
            bfr[ni] = *(const s16x8*)&sm.g.B[buf][(wn * 64 + ni * 16 + lo) * 32 + ((hi ^ fsw) * 8)];
        __builtin_amdgcn_s_setprio(1);
        #pragma unroll
        for (int mi = 0; mi < 8; ++mi)
            #pragma unroll
            for (int ni = 0; ni < 4; ++ni)
                acc[mi][ni] = __builtin_amdgcn_mfma_f32_16x16x32_bf16(
                    af[mi], bfr[ni], acc[mi][ni], 0, 0, 0);
        __builtin_amdgcn_s_setprio(0);
        asm volatile("" ::: "memory");
        __builtin_amdgcn_s_barrier();
    }
    #undef STG

    // ---------------- fused epilogue ----------------
    __syncthreads();   // GEMM LDS dead; safe to reuse union
    // ivs (l0-4 .. l0+263; OOB -> 0 kills halo products)
    for (int i = tid; i < 268; i += 512) {
        int lg = l0 - 4 + i;
        sm.e.ivs[i] = (lg >= 0 && lg < LL) ? invr[b * LL + lg] : 0.f;
    }
    if (tid < 256) {
        int c = d0 + tid;
        float w10 = cw0[3*c], w11 = cw0[3*c+1], w12 = cw0[3*c+2];
        float w20 = cw1[3*c], w21 = cw1[3*c+1], w22 = cw1[3*c+2];
        float w40 = cw2[3*c], w41 = cw2[3*c+1], w42 = cw2[3*c+2];
        float* tp = &sm.e.tapS[tid * 9];
        tp[0] = w40; tp[1] = w20; tp[2] = w10;
        tp[3] = w11 + w21 + w41;
        tp[4] = w12; tp[5] = w22; tp[6] = w42;
        tp[7] = cb0[c] + cb1[c] + cb2[c];
        tp[8] = post_w[c] * lw[c];
        sm.e.gbS[tid] = gate_b[c];
    }
    __syncthreads();
    // stage xnT[c][l] = x * iv * pre_w (bf16), rows c = this block's d-range
    {
        const int c = tid >> 1, h = tid & 1;
        const float* xr = x + ((size_t)(b * CC + d0 + c)) * LL;
        const float pw = pre_w[d0 + c];
        unsigned short* dst = &sm.e.xnT[c * XST];
        #pragma unroll
        for (int j = 0; j < 33; ++j) {
            int li = h * 132 + j * 4;          // tile l-index 0..263
            int lg = l0 - 4 + li;
            int lc = lg < 0 ? 0 : (lg > LL - 4 ? LL - 4 : lg);
            f32x4 v = *(const f32x4*)(xr + lc);
            ushort4 o;
            o.x = f2bf(v[0] * sm.e.ivs[li]     * pw);
            o.y = f2bf(v[1] * sm.e.ivs[li + 1] * pw);
            o.z = f2bf(v[2] * sm.e.ivs[li + 2] * pw);
            o.w = f2bf(v[3] * sm.e.ivs[li + 3] * pw);
            *(ushort4*)(dst + li) = o;
        }
    }
    __syncthreads();
    // conv * silu(acc+gb); accumulate per-l over this lane's c's
    float sq[32] = {}, dp[32] = {};
    #pragma unroll
    for (int mi = 0; mi < 8; ++mi) {
        const int base = wm * 128 + mi * 16 + hi * 4;   // tile l of window start
        #pragma unroll
        for (int ni = 0; ni < 4; ++ni) {
            const int cl = wn * 64 + ni * 16 + lo;
            const unsigned short* xp = &sm.e.xnT[cl * XST + base];
            ushort4 sa = *(const ushort4*)(xp);
            ushort4 sb = *(const ushort4*)(xp + 4);
            ushort4 sc = *(const ushort4*)(xp + 8);
            float s[12];
            s[0] = bf2f(sa.x); s[1] = bf2f(sa.y); s[2]  = bf2f(sa.z); s[3]  = bf2f(sa.w);
            s[4] = bf2f(sb.x); s[5] = bf2f(sb.y); s[6]  = bf2f(sb.z); s[7]  = bf2f(sb.w);
            s[8] = bf2f(sc.x); s[9] = bf2f(sc.y); s[10] = bf2f(sc.z); s[11] = bf2f(sc.w);
            const float* tp = &sm.e.tapS[cl * 9];
            const float gb = sm.e.gbS[cl];
            #pragma unroll
            for (int r = 0; r < 4; ++r) {
                float q = tp[0] * s[r]     + tp[1] * s[r + 2] + tp[2] * s[r + 3]
                        + tp[3] * s[r + 4] + tp[4] * s[r + 5] + tp[5] * s[r + 6]
                        + tp[6] * s[r + 8] + tp[7];
                float z = acc[mi][ni][r] + gb;
                float g = z / (1.0f + __expf(-z));
                float p = q * g;
                sq[mi * 4 + r] += p * p;
                dp[mi * 4 + r] += p * tp[8];
            }
        }
    }
    // reduce over the 16 lo-lanes (c within wave)
    #pragma unroll
    for (int m = 1; m < 16; m <<= 1) {
        #pragma unroll
        for (int k = 0; k < 32; ++k) {
            sq[k] += __shfl_xor(sq[k], m, 64);
            dp[k] += __shfl_xor(dp[k], m, 64);
        }
    }
    if (lo == 0) {
        #pragma unroll
        for (int mi = 0; mi < 8; ++mi)
            #pragma unroll
            for (int r = 0; r < 4; ++r) {
                int ll = wm * 128 + mi * 16 + hi * 4 + r;
                *(float2*)&sm.e.redS[(ll * 4 + wn) * 2] =
                    make_float2(sq[mi * 4 + r], dp[mi * 4 + r]);
            }
    }
    __syncthreads();
    if (tid < 256) {
        float a = 0.f, d2 = 0.f;
        #pragma unroll
        for (int wn2 = 0; wn2 < 4; ++wn2) {
            float2 v = *(const float2*)&sm.e.redS[(tid * 4 + wn2) * 2];
            a += v.x; d2 += v.y;
        }
        *(float2*)&part[(((size_t)(b * 2 + dt)) * LL + l0 + tid) * 2] = make_float2(a, d2);
    }
}

// ------- K3b: combine 2 d-half partials + adx -> out -------
__global__ __launch_bounds__(256) void k3b(
    const float* __restrict__ part, const float* __restrict__ adx,
    float* __restrict__ out) {
    int gl = blockIdx.x * 256 + threadIdx.x;   // B*L = 32768
    int b = gl >> 11, l = gl & 2047;
    float2 p0 = *(const float2*)&part[(((size_t)(b * 2 + 0)) * LL + l) * 2];
    float2 p1 = *(const float2*)&part[(((size_t)(b * 2 + 1)) * LL + l) * 2];
    float sq = p0.x + p1.x, dp = p0.y + p1.y;
    out[gl] = adx[gl] + rsqrtf(sq * (1.0f / CC) + 1e-5f) * dp;
}

extern "C" void kernel_launch(void* const* d_in, const int* in_sizes, int n_in,
                              void* d_out, int out_size, void* d_ws, size_t ws_size,
                              hipStream_t stream) {
    const float* x      = (const float*)d_in[1];
    const float* pre_w  = (const float*)d_in[2];
    const float* cw0    = (const float*)d_in[3];
    const float* cb0    = (const float*)d_in[4];
    const float* cw1    = (const float*)d_in[5];
    const float* cb1    = (const float*)d_in[6];
    const float* cw2    = (const float*)d_in[7];
    const float* cb2    = (const float*)d_in[8];
    const float* gw     = (const float*)d_in[9];
    const float* gb     = (const float*)d_in[10];
    const float* post_w = (const float*)d_in[11];
    const float* lw     = (const float*)d_in[12];
    float* out = (float*)d_out;

    // ws: gwb 0.5MB | xnt 33.5MB | invr 128KB | adx 128KB | part 1MB  (~35.3MB)
    char* ws = (char*)d_ws;
    unsigned short* gwb  = (unsigned short*)(ws);
    unsigned short* xnt  = (unsigned short*)(ws + 524288);
    float*          invr = (float*)(ws + 524288 + 33554432);
    float*          adx  = (float*)(ws + 524288 + 33554432 + 131072);
    float*          part = (float*)(ws + 524288 + 33554432 + 262144);

    hipLaunchKernelGGL(k0_cast,  dim3((CC * CC + 255) / 256), dim3(256), 0, stream, gw, gwb);
    hipLaunchKernelGGL(k1_rms_t, dim3(BB * (LL / 32)),        dim3(256), 0, stream,
                       x, pre_w, lw, xnt, invr, adx);
    hipLaunchKernelGGL(k2f,      dim3(LL / 256, CC / 256, BB), dim3(512), 0, stream,
                       gwb, xnt, x, pre_w, invr, gb,
                       cw0, cb0, cw1, cb1, cw2, cb2, post_w, lw, part);
    hipLaunchKernelGGL(k3b,      dim3(BB * LL / 256),         dim3(256), 0, stream,
                       part, adx, out);
}

// Round 15
// 73.680 us; speedup vs baseline: 1.6450x; 1.6450x over previous
//
#include <hip/hip_runtime.h>
#include <hip/hip_bf16.h>

#define BB 16
#define CC 512
#define LL 2048

typedef float f32x4 __attribute__((ext_vector_type(4)));
typedef short s16x8 __attribute__((ext_vector_type(8)));

static __device__ __forceinline__ float bf2f(unsigned short u) {
    union { unsigned int i; float f; } v; v.i = ((unsigned int)u) << 16; return v.f;
}
static __device__ __forceinline__ unsigned short f2bf(float f) {
    union { float fv; unsigned int i; } v; v.fv = f;
    unsigned int x = v.i;
    return (unsigned short)((x + 0x7FFFu + ((x >> 16) & 1u)) >> 16);  // RNE
}

// ------- K1: RMS over C per (b,l); write inv_rms + x_norm^T bf16 [B][L][C] -------
// Also casts a disjoint 256-element slice of gate_w -> bf16 (k0 folded in).
#define K1_ST 520   // ushort stride (1040 B, 16B-aligned)
__global__ __launch_bounds__(256) void k1_rms_t(
    const float* __restrict__ x, const float* __restrict__ pre_w,
    const float* __restrict__ gw, unsigned short* __restrict__ gwb,
    unsigned short* __restrict__ xnt, float* __restrict__ invr) {
    __shared__ unsigned short tile[32 * K1_ST];   // [l][c] bf16, 33.3 KB
    __shared__ float red[32 * 33];
    __shared__ float pwS[CC];
    __shared__ float ivS[32];
    const int tid = threadIdx.x;
    const int b  = blockIdx.x >> 6;      // 64 l-tiles of 32
    const int lt = blockIdx.x & 63;
    const int l0 = lt * 32;
    const float* xb = x + (size_t)(b * CC) * LL + l0;

    // folded k0: this block casts gw[blockIdx.x*256 + tid]
    {
        int gi = blockIdx.x * 256 + tid;
        gwb[gi] = f2bf(gw[gi]);
    }
    for (int i = tid; i < CC; i += 256) pwS[i] = pre_w[i];

    const int lq = tid & 7;      // l-quad: l = lq*4..+3
    const int cr = tid >> 3;     // 0..31
    f32x4 ssq = {0.f, 0.f, 0.f, 0.f};
    #pragma unroll
    for (int p = 0; p < 16; ++p) {
        int c = p * 32 + cr;
        f32x4 v = *(const f32x4*)(xb + (size_t)c * LL + lq * 4);
        #pragma unroll
        for (int r = 0; r < 4; ++r) {
            ssq[r] += v[r] * v[r];
            tile[(lq * 4 + r) * K1_ST + c] = f2bf(v[r]);
        }
    }
    #pragma unroll
    for (int r = 0; r < 4; ++r) red[(lq * 4 + r) * 33 + cr] = ssq[r];
    __syncthreads();
    if (tid < 32) {
        float s = 0.f;
        #pragma unroll
        for (int g = 0; g < 32; ++g) s += red[tid * 33 + g];
        float iv = rsqrtf(s * (1.0f / CC) + 1e-5f);
        ivS[tid] = iv;
        invr[b * LL + l0 + tid] = iv;
    }
    __syncthreads();
    unsigned short* xo = xnt + ((size_t)b * LL + l0) * CC;
    #pragma unroll
    for (int p = 0; p < 8; ++p) {
        int g = p * 256 + tid;          // 2048 granules of 8 ushorts
        int l = g >> 6, c8 = (g & 63) * 8;
        s16x8 t = *(const s16x8*)&tile[l * K1_ST + c8];
        f32x4 w0 = *(const f32x4*)&pwS[c8];
        f32x4 w1 = *(const f32x4*)&pwS[c8 + 4];
        float iv = ivS[l];
        s16x8 o;
        #pragma unroll
        for (int r = 0; r < 4; ++r) {
            o[r]     = (short)f2bf(bf2f((unsigned short)t[r])     * iv * w0[r]);
            o[r + 4] = (short)f2bf(bf2f((unsigned short)t[r + 4]) * iv * w1[r]);
        }
        *(s16x8*)(xo + (size_t)l * CC + c8) = o;
    }
}

// ------- K2: per-batch GEMM gate[d][l] = silu(sum_c gw[d][c]*xnT[l][c] + gb[d]) -------
// BM=128 x BN=256 tile, BK=32, 16 K-tiles, 8 waves (2Mx4N, 64x64 each).
// 3-buf LDS = 72 KB -> 2 blocks/CU. Counted vmcnt(6) steady-state.
// Granule-XOR swizzle gin^((row>>1)&3) on pre-swizzled source AND frag reads.
__global__ __launch_bounds__(512, 4) void k2_gemm(
    const unsigned short* __restrict__ gwb,   // A [512][512] (d,c) row-major
    const unsigned short* __restrict__ xnt,   // B^T [B][2048][512] (l,c)
    const float* __restrict__ gate_b,
    unsigned short* __restrict__ gate) {      // out bf16 [B][512][2048]
    __shared__ unsigned short As[3][128 * 32];   // 3 x 8 KB
    __shared__ unsigned short Bs[3][256 * 32];   // 3 x 16 KB
    const int tid = threadIdx.x;
    const int w = tid >> 6, lane = tid & 63;
    const int lo = lane & 15, hi = lane >> 4;
    const int wm = w >> 2, wn = w & 3;           // 2M x 4N waves (64x64 each)
    const int nt = blockIdx.x, mt = blockIdx.y, b = blockIdx.z;
    const int m0 = mt * 128, n0 = nt * 256;
    const unsigned short* Ab = gwb;
    const unsigned short* Bb = xnt + (size_t)b * LL * CC;

    #define STG(kt_, buf_)                                                            \
        {                                                                             \
            {                                                                         \
                int row_ = tid >> 2, gin_ = tid & 3;                                  \
                int ks_ = (kt_) * 32 + ((gin_ ^ ((row_ >> 1) & 3)) * 8);              \
                __builtin_amdgcn_global_load_lds(                                     \
                    (const __attribute__((address_space(1))) void*)(Ab + (size_t)(m0 + row_) * CC + ks_), \
                    (__attribute__((address_space(3))) void*)(&As[buf_][tid * 8]),    \
                    16, 0, 0);                                                        \
            }                                                                         \
            _Pragma("unroll")                                                         \
            for (int s_ = 0; s_ < 2; ++s_) {                                          \
                int g_ = tid + s_ * 512;                                              \
                int row_ = g_ >> 2, gin_ = g_ & 3;                                    \
                int ks_ = (kt_) * 32 + ((gin_ ^ ((row_ >> 1) & 3)) * 8);              \
                __builtin_amdgcn_global_load_lds(                                     \
                    (const __attribute__((address_space(1))) void*)(Bb + (size_t)(n0 + row_) * CC + ks_), \
                    (__attribute__((address_space(3))) void*)(&Bs[buf_][g_ * 8]),     \
                    16, 0, 0);                                                        \
            }                                                                         \
        }

    f32x4 acc[4][4] = {};
    const int fsw = (lo >> 1) & 3;     // frag-read granule swizzle (matches source)

    STG(0, 0);
    STG(1, 1);
    #pragma unroll
    for (int kt = 0; kt < 16; ++kt) {
        const int buf = kt % 3;
        if (kt < 14) {
            STG(kt + 2, (kt + 2) % 3);
            asm volatile("s_waitcnt vmcnt(6)" ::: "memory");   // tile kt landed
        } else if (kt == 14) {
            asm volatile("s_waitcnt vmcnt(3)" ::: "memory");
        } else {
            asm volatile("s_waitcnt vmcnt(0)" ::: "memory");
        }
        __builtin_amdgcn_s_barrier();
        s16x8 af[4], bfr[4];
        #pragma unroll
        for (int mi = 0; mi < 4; ++mi)
            af[mi] = *(const s16x8*)&As[buf][(wm * 64 + mi * 16 + lo) * 32 + ((hi ^ fsw) * 8)];
        #pragma unroll
        for (int ni = 0; ni < 4; ++ni)
            bfr[ni] = *(const s16x8*)&Bs[buf][(wn * 64 + ni * 16 + lo) * 32 + ((hi ^ fsw) * 8)];
        __builtin_amdgcn_s_setprio(1);
        #pragma unroll
        for (int mi = 0; mi < 4; ++mi)
            #pragma unroll
            for (int ni = 0; ni < 4; ++ni)
                acc[mi][ni] = __builtin_amdgcn_mfma_f32_16x16x32_bf16(
                    af[mi], bfr[ni], acc[mi][ni], 0, 0, 0);
        __builtin_amdgcn_s_setprio(0);
        asm volatile("" ::: "memory");
        __builtin_amdgcn_s_barrier();   // all reads of buf done before overwrite
    }
    #undef STG

    // epilogue: +bias, SiLU, store bf16. D map: col=lane&15, row=(lane>>4)*4+r
    #pragma unroll
    for (int mi = 0; mi < 4; ++mi) {
        #pragma unroll
        for (int ni = 0; ni < 4; ++ni) {
            int n = n0 + wn * 64 + ni * 16 + lo;
            int d0 = m0 + wm * 64 + mi * 16 + hi * 4;
            #pragma unroll
            for (int r = 0; r < 4; ++r) {
                int d = d0 + r;
                float z = acc[mi][ni][r] + gate_b[d];
                float s = z / (1.0f + __expf(-z));
                gate[((size_t)(b * CC + d)) * LL + n] = f2bf(s);
            }
        }
    }
}

// ------- K3a: fused conv(7 taps)*gate partials over a 64-channel chunk -------
__global__ __launch_bounds__(256) void k3a(
    const float* __restrict__ x, const float* __restrict__ invr,
    const unsigned short* __restrict__ gate,
    const float* __restrict__ cw0, const float* __restrict__ cb0,
    const float* __restrict__ cw1, const float* __restrict__ cb1,
    const float* __restrict__ cw2, const float* __restrict__ cb2,
    const float* __restrict__ pre_w, const float* __restrict__ post_w,
    const float* __restrict__ lw, float* __restrict__ part) {
    __shared__ float tapS[64][8];
    __shared__ float biasS[64], preS[64], lwS[64], pwlwS[64];
    __shared__ float ivs[136];
    __shared__ float red[8][128][3];
    const int tid = threadIdx.x;
    const int lt = blockIdx.x;
    const int cc = blockIdx.y;
    const int b  = blockIdx.z;
    const int l0 = lt * 128;
    const int c0 = cc * 64;

    if (tid < 64) {
        int c = c0 + tid;
        float w10 = cw0[c*3], w11 = cw0[c*3+1], w12 = cw0[c*3+2];
        float w20 = cw1[c*3], w21 = cw1[c*3+1], w22 = cw1[c*3+2];
        float w40 = cw2[c*3], w41 = cw2[c*3+1], w42 = cw2[c*3+2];
        tapS[tid][0] = w40; tapS[tid][1] = w20; tapS[tid][2] = w10;
        tapS[tid][3] = w11 + w21 + w41;
        tapS[tid][4] = w12; tapS[tid][5] = w22; tapS[tid][6] = w42;
        biasS[tid] = cb0[c] + cb1[c] + cb2[c];
        preS[tid]  = pre_w[c];
        float lwc = lw[c];
        lwS[tid] = lwc;
        pwlwS[tid] = post_w[c] * lwc;
    }
    if (tid < 136) {
        int lg = l0 - 4 + tid;
        ivs[tid] = (lg >= 0 && lg < LL) ? invr[b * LL + lg] : 0.f;
    }
    __syncthreads();

    const int li = tid & 31, ci = tid >> 5;
    const int lq = l0 + li * 4;
    float iv[12];
    #pragma unroll
    for (int j = 0; j < 12; ++j) iv[j] = ivs[li * 4 + j];

    const int ia = (lq - 4 < 0) ? 0 : lq - 4;
    const int ic = (lq + 4 > LL - 4) ? LL - 4 : lq + 4;

    float ass[4] = {}, adp[4] = {}, adx[4] = {};
    const float* xbase = x + ((size_t)(b * CC + c0)) * LL;
    const unsigned short* gbase = gate + ((size_t)(b * CC + c0)) * LL;

    #pragma unroll
    for (int j = 0; j < 8; ++j) {
        const int cl = ci * 8 + j;
        const float* xr = xbase + (size_t)cl * LL;
        f32x4 xa = *(const f32x4*)(xr + ia);
        f32x4 xm = *(const f32x4*)(xr + lq);
        f32x4 xc = *(const f32x4*)(xr + ic);
        uint2 gu = *(const uint2*)(gbase + (size_t)cl * LL + lq);
        float g[4];
        g[0] = bf2f((unsigned short)(gu.x & 0xffff));
        g[1] = bf2f((unsigned short)(gu.x >> 16));
        g[2] = bf2f((unsigned short)(gu.y & 0xffff));
        g[3] = bf2f((unsigned short)(gu.y >> 16));
        float z[12];
        #pragma unroll
        for (int r = 0; r < 4; ++r) {
            z[r]     = xa[r] * iv[r];
            z[r + 4] = xm[r] * iv[r + 4];
            z[r + 8] = xc[r] * iv[r + 8];
        }
        const float t0 = tapS[cl][0], t1 = tapS[cl][1], t2 = tapS[cl][2],
                    t3 = tapS[cl][3], t4 = tapS[cl][4], t5 = tapS[cl][5],
                    t6 = tapS[cl][6];
        const float pre = preS[cl], bias = biasS[cl], pwlw = pwlwS[cl], lwc = lwS[cl];
        #pragma unroll
        for (int k = 0; k < 4; ++k) {
            float s = t0 * z[k] + t1 * z[k + 2] + t2 * z[k + 3] + t3 * z[k + 4]
                    + t4 * z[k + 5] + t5 * z[k + 6] + t6 * z[k + 8];
            float p = (pre * s + bias) * g[k];
            ass[k] += p * p;
            adp[k] += p * pwlw;
            adx[k] += xm[k] * lwc;
        }
    }
    #pragma unroll
    for (int k = 0; k < 4; ++k) {
        red[ci][li * 4 + k][0] = ass[k];
        red[ci][li * 4 + k][1] = adp[k];
        red[ci][li * 4 + k][2] = adx[k];
    }
    __syncthreads();
    if (tid < 128) {
        float s0 = 0.f, s1 = 0.f, s2 = 0.f;
        #pragma unroll
        for (int g2 = 0; g2 < 8; ++g2) {
            s0 += red[g2][tid][0];
            s1 += red[g2][tid][1];
            s2 += red[g2][tid][2];
        }
        float* pp = part + (((size_t)(b * 8 + cc)) * LL + l0 + tid) * 3;
        pp[0] = s0; pp[1] = s1; pp[2] = s2;
    }
}

// ------- K3b: combine 8 chunk-partials -> out -------
__global__ __launch_bounds__(256) void k3b(
    const float* __restrict__ part, float* __restrict__ out) {
    int gl = blockIdx.x * 256 + threadIdx.x;   // B*L = 32768
    int b = gl >> 11, l = gl & 2047;
    float s0 = 0.f, s1 = 0.f, s2 = 0.f;
    #pragma unroll
    for (int cc2 = 0; cc2 < 8; ++cc2) {
        const float* pp = part + (((size_t)(b * 8 + cc2)) * LL + l) * 3;
        s0 += pp[0]; s1 += pp[1]; s2 += pp[2];
    }
    out[gl] = s2 + rsqrtf(s0 * (1.0f / CC) + 1e-5f) * s1;
}

extern "C" void kernel_launch(void* const* d_in, const int* in_sizes, int n_in,
                              void* d_out, int out_size, void* d_ws, size_t ws_size,
                              hipStream_t stream) {
    const float* x      = (const float*)d_in[1];
    const float* pre_w  = (const float*)d_in[2];
    const float* cw0    = (const float*)d_in[3];
    const float* cb0    = (const float*)d_in[4];
    const float* cw1    = (const float*)d_in[5];
    const float* cb1    = (const float*)d_in[6];
    const float* cw2    = (const float*)d_in[7];
    const float* cb2    = (const float*)d_in[8];
    const float* gw     = (const float*)d_in[9];
    const float* gb     = (const float*)d_in[10];
    const float* post_w = (const float*)d_in[11];
    const float* lw     = (const float*)d_in[12];
    float* out = (float*)d_out;

    // ws layout (bytes): gw_bf16 0..524288 | x_norm_T 524288..34078720 |
    // inv_rms ..34209792 | gate ..67764224
    // part (3.1MB) aliases x_norm_T (dead after k2).
    char* ws = (char*)d_ws;
    unsigned short* gwb  = (unsigned short*)(ws);
    unsigned short* xnt  = (unsigned short*)(ws + 524288);
    float*          invr = (float*)(ws + 524288 + 33554432);
    unsigned short* gate = (unsigned short*)(ws + 524288 + 33554432 + 131072);
    float*          part = (float*)(ws + 524288);   // alias, dead xnt

    hipLaunchKernelGGL(k1_rms_t, dim3(BB * (LL / 32)),        dim3(256), 0, stream,
                       x, pre_w, gw, gwb, xnt, invr);
    hipLaunchKernelGGL(k2_gemm,  dim3(LL / 256, CC / 128, BB), dim3(512), 0, stream, gwb, xnt, gb, gate);
    hipLaunchKernelGGL(k3a,      dim3(LL / 128, CC / 64, BB), dim3(256), 0, stream,
                       x, invr, gate, cw0, cb0, cw1, cb1, cw2, cb2, pre_w, post_w, lw, part);
    hipLaunchKernelGGL(k3b,      dim3(BB * LL / 256),         dim3(256), 0, stream, part, out);
}